// Round 21
// baseline (200.354 us; speedup 1.0000x reference)
//
#include <hip/hip_runtime.h>

// LightplaneSplatter: trilinear scatter-splat of per-ray encodings (C=16)
// into a (1,128,128,128,16) fp32 grid.
//
// Round 21: largest-work-first chunk dispatch (scan-only change vs R20).
//   R20: accum occupancy 46% vs 75% cap -> scheduling tail: full 1024-record
//   chunks emitted in bin order land late and run nearly alone. Reorder
//   chunk_info: multi-chunk (full) chunks first [0,nMulti), single-chunk
//   bins last [nMulti,nck). Order is correctness-neutral (atomic flush for
//   multi, exclusive tiles for singles). All other kernels byte-identical.

#define NS   64
#define NSI  8
#define ST   (NS + NSI)   // 72
#define GD   128
#define GH   128
#define GW   128
#define GC   16
#define DISP_INF 1e-4f

#define NTT   16                    // tiles per axis (8 points each)
#define NBINS (NTT * NTT * NTT)     // 4096
#define NKEYS (NBINS * 9)           // 36864 (bin x z-bucket)
#define TILE_FL (8 * 8 * 8 * GC)    // 8192 floats = 32 KB
#define CHK   1024                  // samples per chunk
#define MULTI_FLAG 0x80000000u
#define ACC_THREADS 512             // 8 waves, one z-layer each

// ---------------------------------------------------------------------------
__device__ __forceinline__ bool compute_sample(
    const float* __restrict__ dirs, const float* __restrict__ orig,
    const float* __restrict__ nearv, const float* __restrict__ farv,
    int ray, int s,
    int& ix, int& iy, int& iz, float& fx, float& fy, float& fz)
{
    float nr = nearv[ray], fr = farv[ray];
    float t;
    if (s < NS) {
        float frac = ((float)s + 0.5f) * (1.0f / (float)NS);
        t = nr + (fr - nr) * frac;
    } else {
        float j    = (float)(s - NS + 1) * (1.0f / (float)NSI);
        float invf = 1.0f / fr;
        float disp = invf + (DISP_INF - invf) * j;
        t = 1.0f / disp;
    }
    float px = orig[ray*3+0] + t * dirs[ray*3+0];
    float py = orig[ray*3+1] + t * dirs[ray*3+1];
    float pz = orig[ray*3+2] + t * dirs[ray*3+2];
    float vx = (px + 1.0f) * 0.5f * 127.0f;
    float vy = (py + 1.0f) * 0.5f * 127.0f;
    float vz = (pz + 1.0f) * 0.5f * 127.0f;
    float bx = floorf(vx), by = floorf(vy), bz = floorf(vz);
    fx = vx - bx; fy = vy - by; fz = vz - bz;
    ix = (int)bx; iy = (int)by; iz = (int)bz;
    return !(ix < -1 || ix > GW - 1 ||
             iy < -1 || iy > GH - 1 ||
             iz < -1 || iz > GD - 1);
}

// Tile range touched by base cell i along one axis (i in [-1, 127]).
__device__ __forceinline__ void tile_range(int i, int& t0, int& t1)
{
    t0 = (i < 0 ? 0 : i) >> 3;
    t1 = (i + 1 > 127 ? 127 : i + 1) >> 3;
}

// ---------------------------------------------------------------------------
// Passes A (WRITE=false: count) and C (WRITE=true: scatter), shared body.
// Per footprint copy: key = bin*9 + zb. Wave-run aggregation: leader does one
// atomicAdd(cursor[key], runLen); for scatter, lanes write contiguous slots.
// Record: float4 { uint pack = ray<<12 | zb<<8 | (ly0+1)<<4 | (lx0+1),
//                  fx, fy, fz }.
template<bool WRITE>
__global__ __launch_bounds__(256) void bin_kernel(
    const float* __restrict__ dirs, const float* __restrict__ orig,
    const float* __restrict__ nearv, const float* __restrict__ farv,
    int* __restrict__ cursor, float4* __restrict__ recs, int total, int cap)
{
    int idx  = blockIdx.x * 256 + threadIdx.x;
    int lane = threadIdx.x & 63;
    bool act = (idx < total);

    int ix = 0, iy = 0, iz = 0; float fx = 0.f, fy = 0.f, fz = 0.f;
    int tx0 = 0, tx1 = -1, ty0 = 0, ty1 = -1, tz0 = 0, tz1 = -1;
    int ray = 0;
    if (act) {
        ray = idx / ST;
        int s = idx - ray * ST;
        if (compute_sample(dirs, orig, nearv, farv, ray, s, ix, iy, iz, fx, fy, fz)) {
            tile_range(ix, tx0, tx1);
            tile_range(iy, ty0, ty1);
            tile_range(iz, tz0, tz1);
        }
    }

    #pragma unroll
    for (int kz = 0; kz < 2; ++kz)
    #pragma unroll
    for (int ky = 0; ky < 2; ++ky)
    #pragma unroll
    for (int kx = 0; kx < 2; ++kx) {
        int tzi = tz0 + kz, tyi = ty0 + ky, txi = tx0 + kx;
        bool valid = (tzi <= tz1 && tyi <= ty1 && txi <= tx1);
        int zb  = iz - (tzi << 3) + 1;          // in [0,8] when valid
        int key = valid ? ((tzi * NTT + tyi) * NTT + txi) * 9 + zb : -1;

        // Run detection: leader = first lane of a maximal same-key run.
        int prev = __shfl_up(key, 1, 64);
        bool leader = (lane == 0) || (key != prev);
        unsigned long long lm = __ballot(leader);
        unsigned long long below = lm & ((2ull << lane) - 1ull);
        int lead = 63 - __clzll(below);

        int base = 0;
        if (leader && key >= 0) {
            unsigned long long rest = (lane == 63) ? 0ull : (lm >> (lane + 1));
            int next = rest ? (lane + 1 + (__ffsll((long long)rest) - 1)) : 64;
            base = atomicAdd(&cursor[key], next - lane);
        }
        if (WRITE) {
            base = __shfl(base, lead, 64);
            if (key >= 0) {
                int slot = base + (lane - lead);
                if (slot < cap) {
                    unsigned int pk = ((unsigned int)ray << 12)
                                    | ((unsigned int)zb << 8)
                                    | ((unsigned int)(iy - (tyi << 3) + 1) << 4)
                                    |  (unsigned int)(ix - (txi << 3) + 1);
                    recs[slot] = make_float4(__uint_as_float(pk), fx, fy, fz);
                }
            }
        }
    }
}

// ---------------------------------------------------------------------------
// Pass B: scan 36864 key-counts -> offsets/cursor; emit chunk table with
// multi-chunk (full-size) chunks FIRST, single-chunk bins last.
__global__ __launch_bounds__(256) void scan_kernel(
    const int* __restrict__ counts, int* __restrict__ offsets,
    int* __restrict__ cursor, unsigned int* __restrict__ chunk_info,
    int* __restrict__ nck)
{
    __shared__ int p1[256], p2[256], p3[256];
    __shared__ int totMulti;
    const int BPT = NBINS / 256;  // 16 bins (144 keys) per thread
    int tid = threadIdx.x;
    int b0 = tid * BPT;
    int s1 = 0, s2 = 0, s3 = 0;
    for (int i = 0; i < BPT; ++i) {
        int bc = 0;
        for (int j = 0; j < 9; ++j) bc += counts[(b0 + i) * 9 + j];
        s1 += bc;
        int nc = (bc + CHK - 1) / CHK;
        if (nc > 1) s2 += nc;          // multi-chunk chunks
        else if (nc == 1) s3 += 1;     // single-chunk bins
    }
    p1[tid] = s1; p2[tid] = s2; p3[tid] = s3;
    __syncthreads();
    if (tid == 0) {
        int a1 = 0, a2 = 0, a3 = 0;
        for (int i = 0; i < 256; ++i) {
            int v1 = p1[i], v2 = p2[i], v3 = p3[i];
            p1[i] = a1; p2[i] = a2; p3[i] = a3;
            a1 += v1; a2 += v2; a3 += v3;
        }
        totMulti = a2;
        nck[0] = a2 + a3;
    }
    __syncthreads();
    int run   = p1[tid];
    int crunM = p2[tid];               // multi region cursor
    int crunS = totMulti + p3[tid];    // singles region cursor
    for (int i = 0; i < BPT; ++i) {
        int b = b0 + i;
        int binStart = run;
        for (int j = 0; j < 9; ++j) {
            int k = b * 9 + j;
            offsets[k] = run;
            cursor[k]  = run;
            run += counts[k];
        }
        int bc = run - binStart;
        int nc = (bc + CHK - 1) / CHK;
        if (nc > 1) {
            for (int k2 = 0; k2 < nc; ++k2)
                chunk_info[crunM++] =
                    (unsigned int)b | ((unsigned int)k2 << 12) | MULTI_FLAG;
        } else if (nc == 1) {
            chunk_info[crunS++] = (unsigned int)b;
        }
    }
    if (tid == 255) offsets[NKEYS] = run;   // sentinel (global total)
}

// ---------------------------------------------------------------------------
// Zero-fill: one block per bin; zero the bin's 8^3x16 region iff the bin is
// EMPTY (no flush will write it) or MULTI-chunk (atomic flush needs zeroed
// base). Single-chunk bins are fully written by accum's plain-store flush.
__global__ __launch_bounds__(256) void zero_fill(
    const int* __restrict__ offsets, float* __restrict__ grid)
{
    int bin = blockIdx.x;
    int bc = offsets[bin * 9 + 9] - offsets[bin * 9];
    if (bc > 0 && bc <= CHK) return;     // single-chunk bin
    int tx = bin & 15, ty = (bin >> 4) & 15, tz = bin >> 8;
    int gx0 = tx << 3, gy0 = ty << 3, gz0 = tz << 3;
    float4 z = make_float4(0.f, 0.f, 0.f, 0.f);
    for (int i = threadIdx.x; i < TILE_FL / 4; i += 256) {
        int point = i >> 2;
        int q = (i & 3) << 2;
        int lx = point & 7, ly = (point >> 3) & 7, lz = point >> 6;
        size_t gf = (((size_t)((gz0 + lz) * GH + gy0 + ly)) * GW + gx0 + lx) * GC + q;
        *(float4*)&grid[gf] = z;
    }
}

// ---------------------------------------------------------------------------
// Bucket walk: records [lo,hi) of one z-bucket in LDS srec (chunk-local
// coords). 4-record batch ping-pong prefetch; PROC semantics = R15/R17.
template<bool CZ1>
__device__ __forceinline__ void walk_bucket(
    const float* __restrict__ enc, const float4* srec, float* tile,
    int lo, int hi, int wzofs, int cx, int cy, int c, int dxm1, int dym1)
{
    if (lo >= hi) return;
    const int last = hi - 1;

    auto LD = [&](int j, float4& R, float& e) {
        int jj = j < last ? j : last;       // sentinel clamp
        R = srec[jj];
        unsigned sp = __float_as_uint(R.x); // wave-uniform (jj scalar)
        e = enc[((sp >> 12) << 4) + c];
    };
    auto PROCF = [&](const float4& Rc, float ev) {
        unsigned pk = __float_as_uint(Rc.x);
        int lx = (int)(pk & 15u) + dxm1;
        int ly = (int)((pk >> 4) & 15u) + dym1;
        if ((unsigned)(lx | ly) < 8u) {
            float wx = cx ? Rc.y : 1.0f - Rc.y;
            float wy = cy ? Rc.z : 1.0f - Rc.z;
            float wz = CZ1 ? Rc.w : 1.0f - Rc.w;
            int off = ((wzofs + (ly << 3) + lx) << 4) + c;
            tile[off] += (wx * wy) * (wz * ev);
        }
    };

    float4 A0, A1, A2, A3, B0, B1, B2, B3;
    float ea0, ea1, ea2, ea3, eb0, eb1, eb2, eb3;
    LD(lo,     A0, ea0); LD(lo + 1, A1, ea1);
    LD(lo + 2, A2, ea2); LD(lo + 3, A3, ea3);
    int g = lo;
    for (;;) {
        LD(g + 4, B0, eb0); LD(g + 5, B1, eb1);
        LD(g + 6, B2, eb2); LD(g + 7, B3, eb3);
        PROCF(A0, ea0);
        if (g + 1 < hi) PROCF(A1, ea1);
        if (g + 2 < hi) PROCF(A2, ea2);
        if (g + 3 < hi) PROCF(A3, ea3);
        g += 4;
        if (g >= hi) break;

        LD(g + 4, A0, ea0); LD(g + 5, A1, ea1);
        LD(g + 6, A2, ea2); LD(g + 7, A3, ea3);
        PROCF(B0, eb0);
        if (g + 1 < hi) PROCF(B1, eb1);
        if (g + 2 < hi) PROCF(B2, eb2);
        if (g + 3 < hi) PROCF(B3, eb3);
        g += 4;
        if (g >= hi) break;
    }
}

// ---------------------------------------------------------------------------
// Pass D: one block (8 z-slab waves) per chunk. Records arrive z-sorted;
// stage chunk into LDS with a plain coalesced copy, then walk buckets from
// LDS. Wave w walks buckets w (cz=1) and w+1 (cz=0).
__global__ __launch_bounds__(ACC_THREADS, 6) void accum_kernel(
    const float* __restrict__ enc,
    const int* __restrict__ offsets,
    const float4* __restrict__ recs, const unsigned int* __restrict__ chunk_info,
    const int* __restrict__ nck,
    float* __restrict__ grid)
{
    if ((int)blockIdx.x >= nck[0]) return;
    unsigned int info = chunk_info[blockIdx.x];
    int bin  = (int)(info & 0xFFFu);
    int k    = (int)((info >> 12) & 0x7FFFFu);
    bool multi = (info & MULTI_FLAG) != 0;

    int base9 = bin * 9;
    int binStart = offsets[base9];
    int binEnd   = offsets[base9 + 9];
    int start = binStart + k * CHK;
    int end   = start + CHK; if (end > binEnd) end = binEnd;
    int n = end - start;

    int tx = bin & 15, ty = (bin >> 4) & 15, tz = bin >> 8;
    int gx0 = tx << 3, gy0 = ty << 3, gz0 = tz << 3;

    __shared__ float  tile[TILE_FL];   // 32 KB
    __shared__ float4 srec[CHK];       // 16 KB

    int tid = threadIdx.x;
    {
        float4* t4 = (float4*)tile;
        #pragma unroll
        for (int i = tid; i < TILE_FL / 4; i += ACC_THREADS)
            t4[i] = make_float4(0.f, 0.f, 0.f, 0.f);
    }
    // Stage chunk records (already z-sorted) into LDS, coalesced.
    for (int i = tid; i < n; i += ACC_THREADS)
        srec[i] = recs[start + i];
    __syncthreads();

    // Wave w owns z-layer w. Bucket w: cz=1 (wzv = fz); bucket w+1: cz=0.
    int swz  = __builtin_amdgcn_readfirstlane(tid >> 6);
    int lane = tid & 63;
    int c2   = lane >> 4;               // xy-corner 0..3
    int cx   = c2 & 1, cy = c2 >> 1;
    int c    = lane & 15;               // channel
    int dxm1 = cx - 1, dym1 = cy - 1;
    int wzofs = swz << 6;               // wz * 64 points (scalar)

    int rA = offsets[base9 + swz];
    int rM = offsets[base9 + swz + 1];
    int rB = offsets[base9 + swz + 2];

    // Clamp to chunk and rebase to chunk-local srec coords.
    int loA = (rA > start ? rA : start) - start;
    int hiA = (rM < end   ? rM : end)   - start;
    int loB = (rM > start ? rM : start) - start;
    int hiB = (rB < end   ? rB : end)   - start;

    walk_bucket<true >(enc, srec, tile, loA, hiA, wzofs, cx, cy, c, dxm1, dym1);
    walk_bucket<false>(enc, srec, tile, loB, hiB, wzofs, cx, cy, c, dxm1, dym1);

    __syncthreads();

    // Flush. Single-chunk tile: unconditional full-tile store (zeros too --
    // this replaces the global memset for these regions). Multi: zero-skipped
    // atomics onto the zero_fill'ed base.
    if (!multi) {
        const float4* t4 = (const float4*)tile;
        for (int i = tid; i < TILE_FL / 4; i += ACC_THREADS) {
            float4 v = t4[i];
            int point = i >> 2;
            int q = (i & 3) << 2;
            int lx = point & 7, ly = (point >> 3) & 7, lz = point >> 6;
            size_t gf = (((size_t)((gz0 + lz) * GH + gy0 + ly)) * GW + gx0 + lx) * GC + q;
            *(float4*)&grid[gf] = v;
        }
    } else {
        for (int idx = tid; idx < TILE_FL; idx += ACC_THREADS) {
            float v = tile[idx];
            if (v == 0.f) continue;
            int point = idx >> 4, cc = idx & 15;
            int lx = point & 7, ly = (point >> 3) & 7, lz = point >> 6;
            unsafeAtomicAdd(
                &grid[(((gz0 + lz) * GH + gy0 + ly) * GW + gx0 + lx) * GC + cc], v);
        }
    }
}

// ---------------------------------------------------------------------------
// Fallback: direct atomic splat (round-1 kernel) if d_ws is too small.
__global__ __launch_bounds__(256) void splat_direct(
    const float* __restrict__ dirs, const float* __restrict__ orig,
    const float* __restrict__ nearv, const float* __restrict__ farv,
    const float* __restrict__ enc,
    float* __restrict__ grid, int n_rays)
{
    int gt = blockIdx.x * blockDim.x + threadIdx.x;
    int group = gt >> 4;
    int c = gt & 15;
    if (group >= n_rays * ST) return;
    int ray = group / ST;
    int s   = group - ray * ST;
    int ix, iy, iz; float fx, fy, fz;
    if (!compute_sample(dirs, orig, nearv, farv, ray, s, ix, iy, iz, fx, fy, fz))
        return;
    float ev = enc[ray * GC + c];
    float gx0 = 1.0f - fx, gy0 = 1.0f - fy, gz0 = 1.0f - fz;
    #pragma unroll
    for (int corner = 0; corner < 8; ++corner) {
        int cx = corner & 1, cy = (corner >> 1) & 1, cz = (corner >> 2) & 1;
        int jx = ix + cx, jy = iy + cy, jz = iz + cz;
        if (jx < 0 || jx >= GW || jy < 0 || jy >= GH || jz < 0 || jz >= GD) continue;
        float w = (cx ? fx : gx0) * (cy ? fy : gy0) * (cz ? fz : gz0);
        unsafeAtomicAdd(&grid[((jz * GH + jy) * GW + jx) * GC + c], w * ev);
    }
}

// ---------------------------------------------------------------------------
extern "C" void kernel_launch(void* const* d_in, const int* in_sizes, int n_in,
                              void* d_out, int out_size, void* d_ws, size_t ws_size,
                              hipStream_t stream) {
    const float* dirs  = (const float*)d_in[0];
    const float* orig  = (const float*)d_in[1];
    const float* nearv = (const float*)d_in[2];
    const float* farv  = (const float*)d_in[3];
    const float* enc   = (const float*)d_in[4];
    float* out = (float*)d_out;

    int n_rays = in_sizes[2];
    int total  = n_rays * ST;

    // Workspace: [counts(NKEYS)|offsets(NKEYS+1)|cursor(NKEYS)|nck|chunk_info|
    //             (align16) recs(cap)]
    int cap = total + total / 2;                 // record capacity (~1.5x)
    int maxck = NBINS + cap / CHK + 2;           // chunk-table bound
    size_t prefix_ints = (size_t)NKEYS * 3 + 1 + 1 + (size_t)maxck;
    prefix_ints = (prefix_ints + 3) & ~(size_t)3;        // align recs to 16 B
    size_t need = prefix_ints * 4 + (size_t)cap * 16;

    if (ws_size < need || n_rays >= (1 << 20)) {
        hipMemsetAsync(out, 0, (size_t)out_size * sizeof(float), stream);
        long long tthreads = (long long)total * 16;
        int blocks = (int)((tthreads + 255) / 256);
        splat_direct<<<blocks, 256, 0, stream>>>(dirs, orig, nearv, farv, enc,
                                                 out, n_rays);
        return;
    }

    int* counts  = (int*)d_ws;
    int* offsets = counts + NKEYS;       // NKEYS+1 (sentinel)
    int* cursor  = offsets + NKEYS + 1;
    int* nck     = cursor + NKEYS;
    unsigned int* chunk_info = (unsigned int*)(nck + 1);
    float4* recs = (float4*)((int*)d_ws + prefix_ints);

    hipMemsetAsync(counts, 0, NKEYS * sizeof(int), stream);
    int sblocks = (total + 255) / 256;
    bin_kernel<false><<<sblocks, 256, 0, stream>>>(
        dirs, orig, nearv, farv, counts, recs, total, cap);
    scan_kernel<<<1, 256, 0, stream>>>(counts, offsets, cursor, chunk_info, nck);
    zero_fill<<<NBINS, 256, 0, stream>>>(offsets, out);
    bin_kernel<true><<<sblocks, 256, 0, stream>>>(
        dirs, orig, nearv, farv, cursor, recs, total, cap);
    accum_kernel<<<maxck, ACC_THREADS, 0, stream>>>(
        enc, offsets, recs, chunk_info, nck, out);
}

// Round 22
// 183.151 us; speedup vs baseline: 1.0939x; 1.0939x over previous
//
#include <hip/hip_runtime.h>

// LightplaneSplatter: trilinear scatter-splat of per-ray encodings (C=16)
// into a (1,128,128,128,16) fp32 grid.
//
// Round 22: precomputed-decode records (scatter encodes, accum just adds).
//   R21: accum VALU-issue bound (71% busy) at ~22-25 VALU/wave-op, wave-op
//   count already at the 2/record floor. New record pack:
//     pk = ray<<15 | xyValidMask<<11 | (base+144),  base=((ly0<<3)+lx0)<<4
//   so accum's PROC is: validity AND-test (per-lane bit), off = sbase +
//   (pk&2047) + laneDm (2 adds), 2 fma weights, 2 muls, LDS fmac -- ~10
//   VALU/wave-op. zb dropped from records (bucket = position after sort).
//   walk_bucket's LD/ping-pong skeleton unchanged; scan/zero_fill/flush
//   byte-identical to R21.

#define NS   64
#define NSI  8
#define ST   (NS + NSI)   // 72
#define GD   128
#define GH   128
#define GW   128
#define GC   16
#define DISP_INF 1e-4f

#define NTT   16                    // tiles per axis (8 points each)
#define NBINS (NTT * NTT * NTT)     // 4096
#define NKEYS (NBINS * 9)           // 36864 (bin x z-bucket)
#define TILE_FL (8 * 8 * 8 * GC)    // 8192 floats = 32 KB
#define CHK   1024                  // samples per chunk
#define MULTI_FLAG 0x80000000u
#define ACC_THREADS 512             // 8 waves, one z-layer each

// ---------------------------------------------------------------------------
__device__ __forceinline__ bool compute_sample(
    const float* __restrict__ dirs, const float* __restrict__ orig,
    const float* __restrict__ nearv, const float* __restrict__ farv,
    int ray, int s,
    int& ix, int& iy, int& iz, float& fx, float& fy, float& fz)
{
    float nr = nearv[ray], fr = farv[ray];
    float t;
    if (s < NS) {
        float frac = ((float)s + 0.5f) * (1.0f / (float)NS);
        t = nr + (fr - nr) * frac;
    } else {
        float j    = (float)(s - NS + 1) * (1.0f / (float)NSI);
        float invf = 1.0f / fr;
        float disp = invf + (DISP_INF - invf) * j;
        t = 1.0f / disp;
    }
    float px = orig[ray*3+0] + t * dirs[ray*3+0];
    float py = orig[ray*3+1] + t * dirs[ray*3+1];
    float pz = orig[ray*3+2] + t * dirs[ray*3+2];
    float vx = (px + 1.0f) * 0.5f * 127.0f;
    float vy = (py + 1.0f) * 0.5f * 127.0f;
    float vz = (pz + 1.0f) * 0.5f * 127.0f;
    float bx = floorf(vx), by = floorf(vy), bz = floorf(vz);
    fx = vx - bx; fy = vy - by; fz = vz - bz;
    ix = (int)bx; iy = (int)by; iz = (int)bz;
    return !(ix < -1 || ix > GW - 1 ||
             iy < -1 || iy > GH - 1 ||
             iz < -1 || iz > GD - 1);
}

// Tile range touched by base cell i along one axis (i in [-1, 127]).
__device__ __forceinline__ void tile_range(int i, int& t0, int& t1)
{
    t0 = (i < 0 ? 0 : i) >> 3;
    t1 = (i + 1 > 127 ? 127 : i + 1) >> 3;
}

// ---------------------------------------------------------------------------
// Passes A (WRITE=false: count) and C (WRITE=true: scatter), shared body.
// Per footprint copy: key = bin*9 + zb. Wave-run aggregation: leader does one
// atomicAdd(cursor[key], runLen); for scatter, lanes write contiguous slots.
// Record: float4 { uint pk = ray<<15 | mask<<11 | (base+144), fx, fy, fz }
//   base = ((ly0<<3)+lx0)<<4  (lx0,ly0 in [-1,7], tile-relative base cell)
//   mask bit c2 (c2 = cy*2+cx) = corner (cx,cy) lands in-tile (== in-grid).
template<bool WRITE>
__global__ __launch_bounds__(256) void bin_kernel(
    const float* __restrict__ dirs, const float* __restrict__ orig,
    const float* __restrict__ nearv, const float* __restrict__ farv,
    int* __restrict__ cursor, float4* __restrict__ recs, int total, int cap)
{
    int idx  = blockIdx.x * 256 + threadIdx.x;
    int lane = threadIdx.x & 63;
    bool act = (idx < total);

    int ix = 0, iy = 0, iz = 0; float fx = 0.f, fy = 0.f, fz = 0.f;
    int tx0 = 0, tx1 = -1, ty0 = 0, ty1 = -1, tz0 = 0, tz1 = -1;
    int ray = 0;
    if (act) {
        ray = idx / ST;
        int s = idx - ray * ST;
        if (compute_sample(dirs, orig, nearv, farv, ray, s, ix, iy, iz, fx, fy, fz)) {
            tile_range(ix, tx0, tx1);
            tile_range(iy, ty0, ty1);
            tile_range(iz, tz0, tz1);
        }
    }

    #pragma unroll
    for (int kz = 0; kz < 2; ++kz)
    #pragma unroll
    for (int ky = 0; ky < 2; ++ky)
    #pragma unroll
    for (int kx = 0; kx < 2; ++kx) {
        int tzi = tz0 + kz, tyi = ty0 + ky, txi = tx0 + kx;
        bool valid = (tzi <= tz1 && tyi <= ty1 && txi <= tx1);
        int zb  = iz - (tzi << 3) + 1;          // in [0,8] when valid
        int key = valid ? ((tzi * NTT + tyi) * NTT + txi) * 9 + zb : -1;

        // Run detection: leader = first lane of a maximal same-key run.
        int prev = __shfl_up(key, 1, 64);
        bool leader = (lane == 0) || (key != prev);
        unsigned long long lm = __ballot(leader);
        unsigned long long below = lm & ((2ull << lane) - 1ull);
        int lead = 63 - __clzll(below);

        int base = 0;
        if (leader && key >= 0) {
            unsigned long long rest = (lane == 63) ? 0ull : (lm >> (lane + 1));
            int next = rest ? (lane + 1 + (__ffsll((long long)rest) - 1)) : 64;
            base = atomicAdd(&cursor[key], next - lane);
        }
        if (WRITE) {
            base = __shfl(base, lead, 64);
            if (key >= 0) {
                int slot = base + (lane - lead);
                if (slot < cap) {
                    int lx0 = ix - (txi << 3);      // [-1,7]
                    int ly0 = iy - (tyi << 3);      // [-1,7]
                    unsigned vx0 = ((unsigned)lx0 < 8u) ? 1u : 0u;
                    unsigned vx1 = ((unsigned)(lx0 + 1) < 8u) ? 1u : 0u;
                    unsigned vy0 = ((unsigned)ly0 < 8u) ? 1u : 0u;
                    unsigned vy1 = ((unsigned)(ly0 + 1) < 8u) ? 1u : 0u;
                    unsigned mask = (vx0 & vy0) | ((vx1 & vy0) << 1)
                                  | ((vx0 & vy1) << 2) | ((vx1 & vy1) << 3);
                    int bofs = (((ly0 << 3) + lx0) << 4) + 144;  // [0,1152]
                    unsigned int pk = ((unsigned int)ray << 15)
                                    | (mask << 11)
                                    | (unsigned int)bofs;
                    recs[slot] = make_float4(__uint_as_float(pk), fx, fy, fz);
                }
            }
        }
    }
}

// ---------------------------------------------------------------------------
// Pass B: scan 36864 key-counts -> offsets/cursor; emit chunk table with
// multi-chunk (full-size) chunks FIRST, single-chunk bins last.
__global__ __launch_bounds__(256) void scan_kernel(
    const int* __restrict__ counts, int* __restrict__ offsets,
    int* __restrict__ cursor, unsigned int* __restrict__ chunk_info,
    int* __restrict__ nck)
{
    __shared__ int p1[256], p2[256], p3[256];
    __shared__ int totMulti;
    const int BPT = NBINS / 256;  // 16 bins (144 keys) per thread
    int tid = threadIdx.x;
    int b0 = tid * BPT;
    int s1 = 0, s2 = 0, s3 = 0;
    for (int i = 0; i < BPT; ++i) {
        int bc = 0;
        for (int j = 0; j < 9; ++j) bc += counts[(b0 + i) * 9 + j];
        s1 += bc;
        int nc = (bc + CHK - 1) / CHK;
        if (nc > 1) s2 += nc;          // multi-chunk chunks
        else if (nc == 1) s3 += 1;     // single-chunk bins
    }
    p1[tid] = s1; p2[tid] = s2; p3[tid] = s3;
    __syncthreads();
    if (tid == 0) {
        int a1 = 0, a2 = 0, a3 = 0;
        for (int i = 0; i < 256; ++i) {
            int v1 = p1[i], v2 = p2[i], v3 = p3[i];
            p1[i] = a1; p2[i] = a2; p3[i] = a3;
            a1 += v1; a2 += v2; a3 += v3;
        }
        totMulti = a2;
        nck[0] = a2 + a3;
    }
    __syncthreads();
    int run   = p1[tid];
    int crunM = p2[tid];               // multi region cursor
    int crunS = totMulti + p3[tid];    // singles region cursor
    for (int i = 0; i < BPT; ++i) {
        int b = b0 + i;
        int binStart = run;
        for (int j = 0; j < 9; ++j) {
            int k = b * 9 + j;
            offsets[k] = run;
            cursor[k]  = run;
            run += counts[k];
        }
        int bc = run - binStart;
        int nc = (bc + CHK - 1) / CHK;
        if (nc > 1) {
            for (int k2 = 0; k2 < nc; ++k2)
                chunk_info[crunM++] =
                    (unsigned int)b | ((unsigned int)k2 << 12) | MULTI_FLAG;
        } else if (nc == 1) {
            chunk_info[crunS++] = (unsigned int)b;
        }
    }
    if (tid == 255) offsets[NKEYS] = run;   // sentinel (global total)
}

// ---------------------------------------------------------------------------
// Zero-fill: one block per bin; zero the bin's 8^3x16 region iff the bin is
// EMPTY (no flush will write it) or MULTI-chunk (atomic flush needs zeroed
// base). Single-chunk bins are fully written by accum's plain-store flush.
__global__ __launch_bounds__(256) void zero_fill(
    const int* __restrict__ offsets, float* __restrict__ grid)
{
    int bin = blockIdx.x;
    int bc = offsets[bin * 9 + 9] - offsets[bin * 9];
    if (bc > 0 && bc <= CHK) return;     // single-chunk bin
    int tx = bin & 15, ty = (bin >> 4) & 15, tz = bin >> 8;
    int gx0 = tx << 3, gy0 = ty << 3, gz0 = tz << 3;
    float4 z = make_float4(0.f, 0.f, 0.f, 0.f);
    for (int i = threadIdx.x; i < TILE_FL / 4; i += 256) {
        int point = i >> 2;
        int q = (i & 3) << 2;
        int lx = point & 7, ly = (point >> 3) & 7, lz = point >> 6;
        size_t gf = (((size_t)((gz0 + lz) * GH + gy0 + ly)) * GW + gx0 + lx) * GC + q;
        *(float4*)&grid[gf] = z;
    }
}

// ---------------------------------------------------------------------------
// Bucket walk: records [lo,hi) of one z-bucket in LDS srec (chunk-local
// coords). 4-record batch ping-pong prefetch (skeleton = R17/R19 verbatim);
// PROC uses the precomputed pack: validity bit test + 2-add address.
template<bool CZ1>
__device__ __forceinline__ void walk_bucket(
    const float* __restrict__ enc, const float4* srec, float* tile,
    int lo, int hi, int sbase, unsigned vbit, int laneDm, int c,
    float axf, float bxf, float ayf, float byf)
{
    if (lo >= hi) return;
    const int last = hi - 1;

    auto LD = [&](int j, float4& R, float& e) {
        int jj = j < last ? j : last;       // sentinel clamp
        R = srec[jj];
        unsigned sp = __float_as_uint(R.x); // wave-uniform (jj scalar)
        e = enc[((sp >> 15) << 4) + c];
    };
    auto PROCF = [&](const float4& Rc, float ev) {
        unsigned pk = __float_as_uint(Rc.x);
        if (pk & vbit) {
            int off = sbase + (int)(pk & 2047u) + laneDm;
            float wx = fmaf(bxf, Rc.y, axf);
            float wy = fmaf(byf, Rc.z, ayf);
            float wz = CZ1 ? Rc.w : 1.0f - Rc.w;
            tile[off] += (wx * wy) * (wz * ev);
        }
    };

    float4 A0, A1, A2, A3, B0, B1, B2, B3;
    float ea0, ea1, ea2, ea3, eb0, eb1, eb2, eb3;
    LD(lo,     A0, ea0); LD(lo + 1, A1, ea1);
    LD(lo + 2, A2, ea2); LD(lo + 3, A3, ea3);
    int g = lo;
    for (;;) {
        LD(g + 4, B0, eb0); LD(g + 5, B1, eb1);
        LD(g + 6, B2, eb2); LD(g + 7, B3, eb3);
        PROCF(A0, ea0);
        if (g + 1 < hi) PROCF(A1, ea1);
        if (g + 2 < hi) PROCF(A2, ea2);
        if (g + 3 < hi) PROCF(A3, ea3);
        g += 4;
        if (g >= hi) break;

        LD(g + 4, A0, ea0); LD(g + 5, A1, ea1);
        LD(g + 6, A2, ea2); LD(g + 7, A3, ea3);
        PROCF(B0, eb0);
        if (g + 1 < hi) PROCF(B1, eb1);
        if (g + 2 < hi) PROCF(B2, eb2);
        if (g + 3 < hi) PROCF(B3, eb3);
        g += 4;
        if (g >= hi) break;
    }
}

// ---------------------------------------------------------------------------
// Pass D: one block (8 z-slab waves) per chunk. Records arrive z-sorted;
// stage chunk into LDS with a plain coalesced copy, then walk buckets from
// LDS. Wave w walks buckets w (cz=1) and w+1 (cz=0).
__global__ __launch_bounds__(ACC_THREADS, 6) void accum_kernel(
    const float* __restrict__ enc,
    const int* __restrict__ offsets,
    const float4* __restrict__ recs, const unsigned int* __restrict__ chunk_info,
    const int* __restrict__ nck,
    float* __restrict__ grid)
{
    if ((int)blockIdx.x >= nck[0]) return;
    unsigned int info = chunk_info[blockIdx.x];
    int bin  = (int)(info & 0xFFFu);
    int k    = (int)((info >> 12) & 0x7FFFFu);
    bool multi = (info & MULTI_FLAG) != 0;

    int base9 = bin * 9;
    int binStart = offsets[base9];
    int binEnd   = offsets[base9 + 9];
    int start = binStart + k * CHK;
    int end   = start + CHK; if (end > binEnd) end = binEnd;
    int n = end - start;

    int tx = bin & 15, ty = (bin >> 4) & 15, tz = bin >> 8;
    int gx0 = tx << 3, gy0 = ty << 3, gz0 = tz << 3;

    __shared__ float  tile[TILE_FL];   // 32 KB
    __shared__ float4 srec[CHK];       // 16 KB

    int tid = threadIdx.x;
    {
        float4* t4 = (float4*)tile;
        #pragma unroll
        for (int i = tid; i < TILE_FL / 4; i += ACC_THREADS)
            t4[i] = make_float4(0.f, 0.f, 0.f, 0.f);
    }
    // Stage chunk records (already z-sorted) into LDS, coalesced.
    for (int i = tid; i < n; i += ACC_THREADS)
        srec[i] = recs[start + i];
    __syncthreads();

    // Wave w owns z-layer w. Bucket w: cz=1 (wzv = fz); bucket w+1: cz=0.
    int swz  = __builtin_amdgcn_readfirstlane(tid >> 6);
    int lane = tid & 63;
    int c2   = lane >> 4;               // xy-corner 0..3
    int cx   = c2 & 1, cy = c2 >> 1;
    int c    = lane & 15;               // channel
    int sbase = swz << 10;              // wz*64 points * 16 ch (scalar)
    unsigned vbit = 1u << (11 + c2);    // per-lane validity bit
    int laneDm = ((cy << 7) | (cx << 4) | c) - 144;  // undo base bias
    float axf = cx ? 0.f : 1.f, bxf = cx ? 1.f : -1.f;
    float ayf = cy ? 0.f : 1.f, byf = cy ? 1.f : -1.f;

    int rA = offsets[base9 + swz];
    int rM = offsets[base9 + swz + 1];
    int rB = offsets[base9 + swz + 2];

    // Clamp to chunk and rebase to chunk-local srec coords.
    int loA = (rA > start ? rA : start) - start;
    int hiA = (rM < end   ? rM : end)   - start;
    int loB = (rM > start ? rM : start) - start;
    int hiB = (rB < end   ? rB : end)   - start;

    walk_bucket<true >(enc, srec, tile, loA, hiA, sbase, vbit, laneDm, c,
                       axf, bxf, ayf, byf);
    walk_bucket<false>(enc, srec, tile, loB, hiB, sbase, vbit, laneDm, c,
                       axf, bxf, ayf, byf);

    __syncthreads();

    // Flush. Single-chunk tile: unconditional full-tile store (zeros too --
    // this replaces the global memset for these regions). Multi: zero-skipped
    // atomics onto the zero_fill'ed base.
    if (!multi) {
        const float4* t4 = (const float4*)tile;
        for (int i = tid; i < TILE_FL / 4; i += ACC_THREADS) {
            float4 v = t4[i];
            int point = i >> 2;
            int q = (i & 3) << 2;
            int lx = point & 7, ly = (point >> 3) & 7, lz = point >> 6;
            size_t gf = (((size_t)((gz0 + lz) * GH + gy0 + ly)) * GW + gx0 + lx) * GC + q;
            *(float4*)&grid[gf] = v;
        }
    } else {
        for (int idx = tid; idx < TILE_FL; idx += ACC_THREADS) {
            float v = tile[idx];
            if (v == 0.f) continue;
            int point = idx >> 4, cc = idx & 15;
            int lx = point & 7, ly = (point >> 3) & 7, lz = point >> 6;
            unsafeAtomicAdd(
                &grid[(((gz0 + lz) * GH + gy0 + ly) * GW + gx0 + lx) * GC + cc], v);
        }
    }
}

// ---------------------------------------------------------------------------
// Fallback: direct atomic splat (round-1 kernel) if d_ws is too small.
__global__ __launch_bounds__(256) void splat_direct(
    const float* __restrict__ dirs, const float* __restrict__ orig,
    const float* __restrict__ nearv, const float* __restrict__ farv,
    const float* __restrict__ enc,
    float* __restrict__ grid, int n_rays)
{
    int gt = blockIdx.x * blockDim.x + threadIdx.x;
    int group = gt >> 4;
    int c = gt & 15;
    if (group >= n_rays * ST) return;
    int ray = group / ST;
    int s   = group - ray * ST;
    int ix, iy, iz; float fx, fy, fz;
    if (!compute_sample(dirs, orig, nearv, farv, ray, s, ix, iy, iz, fx, fy, fz))
        return;
    float ev = enc[ray * GC + c];
    float gx0 = 1.0f - fx, gy0 = 1.0f - fy, gz0 = 1.0f - fz;
    #pragma unroll
    for (int corner = 0; corner < 8; ++corner) {
        int cx = corner & 1, cy = (corner >> 1) & 1, cz = (corner >> 2) & 1;
        int jx = ix + cx, jy = iy + cy, jz = iz + cz;
        if (jx < 0 || jx >= GW || jy < 0 || jy >= GH || jz < 0 || jz >= GD) continue;
        float w = (cx ? fx : gx0) * (cy ? fy : gy0) * (cz ? fz : gz0);
        unsafeAtomicAdd(&grid[((jz * GH + jy) * GW + jx) * GC + c], w * ev);
    }
}

// ---------------------------------------------------------------------------
extern "C" void kernel_launch(void* const* d_in, const int* in_sizes, int n_in,
                              void* d_out, int out_size, void* d_ws, size_t ws_size,
                              hipStream_t stream) {
    const float* dirs  = (const float*)d_in[0];
    const float* orig  = (const float*)d_in[1];
    const float* nearv = (const float*)d_in[2];
    const float* farv  = (const float*)d_in[3];
    const float* enc   = (const float*)d_in[4];
    float* out = (float*)d_out;

    int n_rays = in_sizes[2];
    int total  = n_rays * ST;

    // Workspace: [counts(NKEYS)|offsets(NKEYS+1)|cursor(NKEYS)|nck|chunk_info|
    //             (align16) recs(cap)]
    int cap = total + total / 2;                 // record capacity (~1.5x)
    int maxck = NBINS + cap / CHK + 2;           // chunk-table bound
    size_t prefix_ints = (size_t)NKEYS * 3 + 1 + 1 + (size_t)maxck;
    prefix_ints = (prefix_ints + 3) & ~(size_t)3;        // align recs to 16 B
    size_t need = prefix_ints * 4 + (size_t)cap * 16;

    // ray field in the record pack is 17 bits.
    if (ws_size < need || n_rays >= (1 << 17)) {
        hipMemsetAsync(out, 0, (size_t)out_size * sizeof(float), stream);
        long long tthreads = (long long)total * 16;
        int blocks = (int)((tthreads + 255) / 256);
        splat_direct<<<blocks, 256, 0, stream>>>(dirs, orig, nearv, farv, enc,
                                                 out, n_rays);
        return;
    }

    int* counts  = (int*)d_ws;
    int* offsets = counts + NKEYS;       // NKEYS+1 (sentinel)
    int* cursor  = offsets + NKEYS + 1;
    int* nck     = cursor + NKEYS;
    unsigned int* chunk_info = (unsigned int*)(nck + 1);
    float4* recs = (float4*)((int*)d_ws + prefix_ints);

    hipMemsetAsync(counts, 0, NKEYS * sizeof(int), stream);
    int sblocks = (total + 255) / 256;
    bin_kernel<false><<<sblocks, 256, 0, stream>>>(
        dirs, orig, nearv, farv, counts, recs, total, cap);
    scan_kernel<<<1, 256, 0, stream>>>(counts, offsets, cursor, chunk_info, nck);
    zero_fill<<<NBINS, 256, 0, stream>>>(offsets, out);
    bin_kernel<true><<<sblocks, 256, 0, stream>>>(
        dirs, orig, nearv, farv, cursor, recs, total, cap);
    accum_kernel<<<maxck, ACC_THREADS, 0, stream>>>(
        enc, offsets, recs, chunk_info, nck, out);
}